// Round 7
// baseline (134.003 us; speedup 1.0000x reference)
//
#include <hip/hip_runtime.h>

#define Bn 2
#define Ln 2048
#define DIN 256
#define Hn 8
#define DEPTH 32
#define SCALE 0.17677669529663687f      // 1/sqrt(32)
#define NEGC (-4294967296.0f)           // float32(-2^32+1)
#define NG  (Ln / 16)                   // 128 16-row groups per (b,h)
#define WLS 264                         // LDS W^T row stride (f16) [fallback]

typedef _Float16 f16;
typedef _Float16 h8 __attribute__((ext_vector_type(8)));   // K=32 A/B frag
typedef _Float16 h4 __attribute__((ext_vector_type(4)));   // K=16 A/B frag
typedef float f4 __attribute__((ext_vector_type(4)));      // C/D frag

// ===========================================================================
// MAIN PATH (ws >= 8 MB). Per-iteration budget analysis (R5/R6 A/B): the
// ~42us 268MB ws poison-fill is an unconditional harness tax, and the
// iteration carries ~17 dispatches (fill + kernels + input restores) of
// launch overhead.  Lever: fewer/faster kernel dispatches.
//   L1 proj_gemm (768 blk, no-LDS): QKV -> Qz (pre-scaled), Kz, Vz in ws
//   L2 flash_out (128 blk x 1024 thr): block = (b, 32 q-rows), 16 waves =
//      (head, key-half).  Flash (64 groups/wave serial) -> LDS combine ->
//      in-block out-projection @ Wo -> out.  No Oz round-trip, no 3rd launch.
// Frag-swizzled ws layouts (proven):
//   Qz/Kz chunk per (hb, 16-row group g) = 512 f16: lane(quad*16+l15) holds
//     8 f16 = row (g*16+l15), depth (quad*8..+7).
//   Vz per (hb,g): 2 half-chunks of 256 f16 (d-halves); lane holds 4 f16 =
//     V[key=g*16+quad*4+j][d=dhalf*16+l15].
// ===========================================================================

// ---- Kernel 1: QKV projection, no LDS. Wave = 16m x 64n tile. -------------
__global__ __launch_bounds__(256) void proj_gemm(
    const float* __restrict__ Xq, const float* __restrict__ Xk, const float* __restrict__ Xv,
    const float* __restrict__ Wq, const float* __restrict__ Wk, const float* __restrict__ Wv,
    const float* __restrict__ bq, const float* __restrict__ bk, const float* __restrict__ bv,
    f16* __restrict__ Qz, f16* __restrict__ Kz, f16* __restrict__ Vz)
{
    const int p = blockIdx.z;
    const float* X = p == 0 ? Xq : p == 1 ? Xk : Xv;
    const float* W = p == 0 ? Wq : p == 1 ? Wk : Wv;
    const float* bias = p == 0 ? bq : p == 1 ? bk : bv;

    const int t = threadIdx.x, w = t >> 6, lane = t & 63;
    const int l15 = lane & 15, quad = lane >> 4;
    const int n0 = blockIdx.y * 64;
    const int m0 = blockIdx.x * 64 + w * 16;

    const float* A0 = X + (size_t)(m0 + l15) * DIN;
    const float* Wp = W + n0 + l15;          // this lane's n-column base

    f4 acc[4] = {{0.f,0.f,0.f,0.f},{0.f,0.f,0.f,0.f},
                 {0.f,0.f,0.f,0.f},{0.f,0.f,0.f,0.f}};
    #pragma unroll
    for (int kk = 0; kk < 8; ++kk) {
        const int k0 = kk * 32;
        float4 xa = *(const float4*)(A0 + k0 + quad * 8);
        float4 xb = *(const float4*)(A0 + k0 + quad * 8 + 4);
        h8 af = { (f16)xa.x, (f16)xa.y, (f16)xa.z, (f16)xa.w,
                  (f16)xb.x, (f16)xb.y, (f16)xb.z, (f16)xb.w };
        h8 bf[4];
        #pragma unroll
        for (int tt = 0; tt < 4; ++tt)
            #pragma unroll
            for (int j = 0; j < 8; ++j)
                bf[tt][j] = (f16)Wp[(size_t)(k0 + quad * 8 + j) * DIN + tt * 16];
        #pragma unroll
        for (int tt = 0; tt < 4; ++tt)
            acc[tt] = __builtin_amdgcn_mfma_f32_16x16x32_f16(af, bf[tt], acc[tt], 0, 0, 0);
    }
    #pragma unroll
    for (int tt = 0; tt < 4; ++tt) {
        const int c = n0 + tt * 16 + l15;        // 16-tile never straddles a head
        const float bb = bias[c];
        const int h = c >> 5, dd = c & 31;
        #pragma unroll
        for (int r = 0; r < 4; ++r) {
            const int row = m0 + quad * 4 + r;
            const int b = row >> 11, l = row & (Ln - 1);
            const float v = acc[tt][r] + bb;
            const size_t hbg = (size_t)(b * Hn + h) * NG + (l >> 4);
            if (p == 0)        // Q swizzled (K=32 B-frag chunks), pre-scaled
                Qz[(hbg * 64 + (dd >> 3) * 16 + (l & 15)) * 8 + (dd & 7)] =
                    (f16)(v * SCALE);
            else if (p == 1)   // K swizzled (K=32 A-frag chunks)
                Kz[(hbg * 64 + (dd >> 3) * 16 + (l & 15)) * 8 + (dd & 7)] = (f16)v;
            else               // V swizzled (K=16 A-frag chunks, 2 d-halves)
                Vz[((hbg * 2 + (dd >> 4)) * 64 + ((l & 15) >> 2) * 16 + (dd & 15)) * 4
                   + (l & 3)] = (f16)v;
        }
    }
}

// ---- Kernel 2: fused flash + out-projection. ------------------------------
// Grid 128 (XCD-chunk-swizzled): block = (b, 32 q-rows).  16 waves; wave w =
// (h = w>>1, half = w&1) runs 64 key-groups of head h.  LDS combine builds
// O (32 x 256 f16), then each wave MFMAs a 16x32 out-tile against Wo.
__global__ __launch_bounds__(1024) void flash_out(
    const f16* __restrict__ Qz, const f16* __restrict__ Kz,
    const f16* __restrict__ Vz, const int* __restrict__ mask,
    const float* __restrict__ Wo, const float* __restrict__ bo,
    float* __restrict__ out)
{
    __shared__ union {
        struct { float Os[16][32][34]; float lS[16][32]; } c;  // 71.7 KB
        f16 Of[32 * 264];                                      // 16.9 KB
    } sm;
    const int t = threadIdx.x, w = t >> 6, lane = t & 63;
    const int l15 = lane & 15, quad = lane >> 4;
    const int bid = blockIdx.x;
    const int swz = (bid & 7) * 16 + (bid >> 3);   // 128 = 8 XCD x 16: bijective
    const int b = swz >> 6, qidx = swz & 63;
    const int q0 = qidx * 32;
    const int h = w >> 1, half = w & 1;
    const int hb = b * Hn + h;
    const f16* Qh = Qz + (size_t)hb * NG * 512;
    const f16* Kh = Kz + (size_t)hb * NG * 512;
    const f16* Vh = Vz + (size_t)hb * NG * 512;
    const int* mrow = mask + b * Ln;

    // ---- flash phase: 64 groups (keys [half*1024, half*1024+1024)) ----
    h8 qf[2];
    #pragma unroll
    for (int qg = 0; qg < 2; ++qg)
        qf[qg] = *(const h8*)(Qh + ((size_t)(qidx * 2 + qg) * 64 + lane) * 8);

    f4 o[2][2];                                 // [d-half][q-group]
    #pragma unroll
    for (int i = 0; i < 2; ++i)
        #pragma unroll
        for (int j = 0; j < 2; ++j) o[i][j] = (f4){0.f, 0.f, 0.f, 0.f};
    float l_run[2] = {0.f, 0.f};                // per-lane q = q0 + qg*16 + l15

    for (int kt = 0; kt < 16; ++kt) {
        #pragma unroll
        for (int tt = 0; tt < 4; ++tt) {
            const int g = half * 64 + kt * 4 + tt;     // group 0..127
            h8 kf = *(const h8*)(Kh + ((size_t)g * 64 + lane) * 8);
            const int4 mk = *(const int4*)(mrow + g * 16 + quad * 4);
            f4 bias4 = { mk.x ? 0.f : NEGC, mk.y ? 0.f : NEGC,
                         mk.z ? 0.f : NEGC, mk.w ? 0.f : NEGC };
            h4 va0 = *(const h4*)(Vh + ((size_t)(g * 2)     * 64 + lane) * 4);
            h4 va1 = *(const h4*)(Vh + ((size_t)(g * 2 + 1) * 64 + lane) * 4);
            f4 s[2];
            #pragma unroll
            for (int qg = 0; qg < 2; ++qg)
                s[qg] = __builtin_amdgcn_mfma_f32_16x16x32_f16(kf, qf[qg], bias4, 0, 0, 0);
            #pragma unroll
            for (int qg = 0; qg < 2; ++qg) {
                h4 pf;
                #pragma unroll
                for (int r = 0; r < 4; ++r) {
                    const float pv = __expf(s[qg][r]);
                    l_run[qg] += pv;
                    pf[r] = (f16)pv;
                }
                o[0][qg] = __builtin_amdgcn_mfma_f32_16x16x16f16(va0, pf, o[0][qg], 0, 0, 0);
                o[1][qg] = __builtin_amdgcn_mfma_f32_16x16x16f16(va1, pf, o[1][qg], 0, 0, 0);
            }
        }
    }
    // ---- wave partials into LDS ----
    #pragma unroll
    for (int qg = 0; qg < 2; ++qg) {
        l_run[qg] += __shfl_xor(l_run[qg], 16, 64);
        l_run[qg] += __shfl_xor(l_run[qg], 32, 64);
        if (quad == 0) sm.c.lS[w][qg * 16 + l15] = l_run[qg];
        #pragma unroll
        for (int dg = 0; dg < 2; ++dg)
            #pragma unroll
            for (int r = 0; r < 4; ++r)
                sm.c.Os[w][dg * 16 + quad * 4 + r][qg * 16 + l15] = o[dg][qg][r];
    }
    __syncthreads();

    // ---- combine 2 key-halves per head -> registers ----
    // thread (q = t&31, co = t>>5): cols c = co*8 .. co*8+7 (one head).
    const int cq = t & 31, co = t >> 5;
    const int ch = co >> 2, dd0 = (co & 3) * 8;
    h8 opack;
    {
        const float ls = sm.c.lS[2 * ch][cq] + sm.c.lS[2 * ch + 1][cq];
        const float inv = 1.0f / ls;
        #pragma unroll
        for (int i = 0; i < 8; ++i) {
            const float ov = sm.c.Os[2 * ch][dd0 + i][cq]
                           + sm.c.Os[2 * ch + 1][dd0 + i][cq];
            opack[i] = (f16)(ov * inv);
        }
    }
    __syncthreads();                      // all Os/lS reads done
    *(h8*)(sm.Of + cq * 264 + co * 8) = opack;
    __syncthreads();                      // Of ready

    // ---- out-projection: wave w = (rt = w>>3, col-pair = w&7) ----
    {
        const int rt = w >> 3, tp = w & 7;
        h8 af[8];
        #pragma unroll
        for (int kk = 0; kk < 8; ++kk)
            af[kk] = *(const h8*)(sm.Of + (rt * 16 + l15) * 264 + kk * 32 + quad * 8);

        const float* Wop = Wo + tp * 32 + l15;
        f4 acc[2] = {{0.f,0.f,0.f,0.f},{0.f,0.f,0.f,0.f}};
        #pragma unroll
        for (int kk = 0; kk < 8; ++kk) {
            h8 bf[2];
            #pragma unroll
            for (int i = 0; i < 2; ++i)
                #pragma unroll
                for (int j = 0; j < 8; ++j)
                    bf[i][j] = (f16)Wop[(size_t)(kk * 32 + quad * 8 + j) * DIN + i * 16];
            #pragma unroll
            for (int i = 0; i < 2; ++i)
                acc[i] = __builtin_amdgcn_mfma_f32_16x16x32_f16(af[kk], bf[i], acc[i], 0, 0, 0);
        }
        #pragma unroll
        for (int i = 0; i < 2; ++i) {
            const int c = tp * 32 + i * 16 + l15;
            const float bb = bo[c];
            #pragma unroll
            for (int r = 0; r < 4; ++r) {
                const int row = q0 + rt * 16 + quad * 4 + r;
                out[(size_t)(b * Ln + row) * DIN + c] = acc[i][r] + bb;
            }
        }
    }
}

// ===========================================================================
// FALLBACK (ws < 8 MB): proven R4 zero-workspace self-aliasing 5-launch path.
// ===========================================================================
__global__ __launch_bounds__(256) void fb_projKV(
    const float* __restrict__ Xk, const float* __restrict__ Xv,
    const float* __restrict__ Wk, const float* __restrict__ Wv,
    const float* __restrict__ bk, const float* __restrict__ bv,
    f16* S, int b)
{
    __shared__ f16 Wl[64 * WLS];
    const int p = blockIdx.z;
    const float* X = (p ? Xv : Xk) + (size_t)b * Ln * DIN;
    const float* W = p ? Wv : Wk;
    const float* bias = p ? bv : bk;

    const int t = threadIdx.x, w = t >> 6, lane = t & 63;
    const int l15 = lane & 15, quad = lane >> 4;
    const int n0 = blockIdx.y * 64;

    {
        const int nl = t & 63, kb = t >> 6;
        for (int kk = 0; kk < 64; ++kk) {
            const int k = kk * 4 + kb;
            Wl[nl * WLS + k] = (f16)W[(size_t)k * DIN + n0 + nl];
        }
    }
    __syncthreads();

    const int m0w = blockIdx.x * 128 + w * 32;
    const float* A0 = X + (size_t)(m0w + l15) * DIN;
    const float* A1 = X + (size_t)(m0w + 16 + l15) * DIN;

    f4 acc[2][4];
    #pragma unroll
    for (int mi = 0; mi < 2; ++mi)
        #pragma unroll
        for (int tt = 0; tt < 4; ++tt) acc[mi][tt] = (f4){0.f, 0.f, 0.f, 0.f};

    for (int k0 = 0; k0 < DIN; k0 += 32) {
        float4 xa0 = *(const float4*)(A0 + k0 + quad * 8);
        float4 xb0 = *(const float4*)(A0 + k0 + quad * 8 + 4);
        float4 xa1 = *(const float4*)(A1 + k0 + quad * 8);
        float4 xb1 = *(const float4*)(A1 + k0 + quad * 8 + 4);
        h8 af0 = { (f16)xa0.x, (f16)xa0.y, (f16)xa0.z, (f16)xa0.w,
                   (f16)xb0.x, (f16)xb0.y, (f16)xb0.z, (f16)xb0.w };
        h8 af1 = { (f16)xa1.x, (f16)xa1.y, (f16)xa1.z, (f16)xa1.w,
                   (f16)xb1.x, (f16)xb1.y, (f16)xb1.z, (f16)xb1.w };
        #pragma unroll
        for (int tt = 0; tt < 4; ++tt) {
            h8 bf = *(const h8*)(Wl + (tt * 16 + l15) * WLS + k0 + quad * 8);
            acc[0][tt] = __builtin_amdgcn_mfma_f32_16x16x32_f16(af0, bf, acc[0][tt], 0, 0, 0);
            acc[1][tt] = __builtin_amdgcn_mfma_f32_16x16x32_f16(af1, bf, acc[1][tt], 0, 0, 0);
        }
    }
    #pragma unroll
    for (int mi = 0; mi < 2; ++mi)
        #pragma unroll
        for (int tt = 0; tt < 4; ++tt) {
            const int c = n0 + tt * 16 + l15;
            const float bb = bias[c];
            const int h = c >> 5, dd = c & 31;
            #pragma unroll
            for (int r = 0; r < 4; ++r) {
                const int l = m0w + mi * 16 + quad * 4 + r;
                const float v = acc[mi][tt][r] + bb;
                const unsigned hg = (unsigned)h * 128 + (l >> 4);
                unsigned j;
                if (!p)
                    j = (hg * 64 + (unsigned)(dd >> 3) * 16 + (l & 15)) * 8 + (dd & 7);
                else
                    j = 524288u + ((hg * 2 + (dd >> 4)) * 64
                        + (unsigned)((l & 15) >> 2) * 16 + (dd & 15)) * 4 + (l & 3);
                S[(((size_t)(j >> 12)) << 13) + 4096u + (j & 4095u)] = (f16)v;
            }
        }
}

__global__ __launch_bounds__(512) void fb_flashQ(
    const float* __restrict__ Xq, const float* __restrict__ Wq,
    const float* __restrict__ bq, const int* __restrict__ mask,
    float* outbuf, int b)
{
    __shared__ union {
        struct { f16 Wlq[32 * WLS]; f16 Qs[2048]; } a;
        struct { float Os[8][32][68]; float lS[8][64]; } c;
    } sm;
    f16* S = (f16*)outbuf;
    const int t = threadIdx.x, w = t >> 6, lane = t & 63;
    const int l15 = lane & 15, quad = lane >> 4;
    const int h = blockIdx.x, q0 = blockIdx.y * 64;

    {
        const int nl = t & 31, kb = t >> 5;
        for (int kk = 0; kk < 16; ++kk) {
            const int k = kk * 16 + kb;
            sm.a.Wlq[nl * WLS + k] = (f16)Wq[(size_t)k * DIN + h * 32 + nl];
        }
    }
    __syncthreads();

    if (w < 4) {
        const float* A0 = Xq + (size_t)(b * Ln + q0 + w * 16 + l15) * DIN;
        f4 a2[2] = { {0.f,0.f,0.f,0.f}, {0.f,0.f,0.f,0.f} };
        #pragma unroll
        for (int kk = 0; kk < 8; ++kk) {
            const int k0 = kk * 32;
            float4 xa = *(const float4*)(A0 + k0 + quad * 8);
            float4 xb = *(const float4*)(A0 + k0 + quad * 8 + 4);
            h8 af = { (f16)xa.x, (f16)xa.y, (f16)xa.z, (f16)xa.w,
                      (f16)xb.x, (f16)xb.y, (f16)xb.z, (f16)xb.w };
            #pragma unroll
            for (int tt = 0; tt < 2; ++tt) {
                h8 bf = *(const h8*)(sm.a.Wlq + (tt * 16 + l15) * WLS + k0 + quad * 8);
                a2[tt] = __builtin_amdgcn_mfma_f32_16x16x32_f16(af, bf, a2[tt], 0, 0, 0);
            }
        }
        #pragma unroll
        for (int tt = 0; tt < 2; ++tt) {
            const int c = tt * 16 + l15;
            const float bb = bq[h * 32 + c];
            #pragma unroll
            for (int r = 0; r < 4; ++r) {
                const int lc = quad * 4 + r;
                sm.a.Qs[((size_t)w * 64 + (c >> 3) * 16 + lc) * 8 + (c & 7)] =
                    (f16)((a2[tt][r] + bb) * SCALE);
            }
        }
    }
    __syncthreads();
    h8 qf[4];
    #pragma unroll
    for (int qg = 0; qg < 4; ++qg)
        qf[qg] = *(const h8*)(sm.a.Qs + ((size_t)qg * 64 + lane) * 8);
    __syncthreads();

    const int* mrow = mask + b * Ln;
    f4 o[2][4];
    #pragma unroll
    for (int i = 0; i < 2; ++i)
        #pragma unroll
        for (int j = 0; j < 4; ++j) o[i][j] = (f4){0.f, 0.f, 0.f, 0.f};
    float l_run[4] = {0.f, 0.f, 0.f, 0.f};
    const int k_base = w * (Ln / 8);

    for (int kt = 0; kt < Ln / 8 / 64; ++kt) {
        const int k0 = k_base + kt * 64;
        #pragma unroll
        for (int tt = 0; tt < 4; ++tt) {
            const int g = (k0 >> 4) + tt;
            const size_t kaddr = ((size_t)(h * 16 + (g >> 3)) << 13) + 4096u
                               + (size_t)((g & 7) * 512 + lane * 8);
            h8 kf = *(const h8*)(S + kaddr);
            const int4 mk = *(const int4*)(mrow + g * 16 + quad * 4);
            f4 bias4 = { mk.x ? 0.f : NEGC, mk.y ? 0.f : NEGC,
                         mk.z ? 0.f : NEGC, mk.w ? 0.f : NEGC };
            const size_t vaddr = ((size_t)(128 + h * 16 + (g >> 3)) << 13) + 4096u
                               + (size_t)((g & 7) * 512 + lane * 4);
            h4 va0 = *(const h4*)(S + vaddr);
            h4 va1 = *(const h4*)(S + vaddr + 256);
            f4 s_[4];
            #pragma unroll
            for (int qg = 0; qg < 4; ++qg)
                s_[qg] = __builtin_amdgcn_mfma_f32_16x16x32_f16(kf, qf[qg], bias4, 0, 0, 0);
            #pragma unroll
            for (int qg = 0; qg < 4; ++qg) {
                h4 pf;
                #pragma unroll
                for (int r = 0; r < 4; ++r) {
                    const float pv = __expf(s_[qg][r]);
                    l_run[qg] += pv;
                    pf[r] = (f16)pv;
                }
                o[0][qg] = __builtin_amdgcn_mfma_f32_16x16x16f16(va0, pf, o[0][qg], 0, 0, 0);
                o[1][qg] = __builtin_amdgcn_mfma_f32_16x16x16f16(va1, pf, o[1][qg], 0, 0, 0);
            }
        }
    }
    #pragma unroll
    for (int qg = 0; qg < 4; ++qg) {
        l_run[qg] += __shfl_xor(l_run[qg], 16, 64);
        l_run[qg] += __shfl_xor(l_run[qg], 32, 64);
        if (quad == 0) sm.c.lS[w][qg * 16 + l15] = l_run[qg];
        #pragma unroll
        for (int dg = 0; dg < 2; ++dg)
            #pragma unroll
            for (int r = 0; r < 4; ++r)
                sm.c.Os[w][dg * 16 + quad * 4 + r][qg * 16 + l15] = o[dg][qg][r];
    }
    __syncthreads();

    if (t < 256) {
        const int cq = t & 63, dv = t >> 6;
        float ls = 0.f;
        #pragma unroll
        for (int i = 0; i < 8; ++i) ls += sm.c.lS[i][cq];
        const float inv = 1.0f / ls;
        h8 pack;
        #pragma unroll
        for (int i = 0; i < 8; ++i) {
            const int dd = dv * 8 + i;
            float ov = 0.f;
            #pragma unroll
            for (int s = 0; s < 8; ++s) ov += sm.c.Os[s][dd][cq];
            pack[i] = (f16)(ov * inv);
        }
        const int gm = b * 128 + ((q0 + cq) >> 4);
        *(h8*)(S + (size_t)gm * 8192
               + (size_t)(h * 64 + dv * 16 + (cq & 15)) * 8) = pack;
    }
}

__global__ __launch_bounds__(256) void fb_outproj(
    const float* __restrict__ Wo, const float* __restrict__ bo, float* outbuf)
{
    f16* S = (f16*)outbuf;
    const int t = threadIdx.x, w = t >> 6, lane = t & 63;
    const int l15 = lane & 15, quad = lane >> 4;
    const int g = blockIdx.x;

    h8 af[8];
    #pragma unroll
    for (int h = 0; h < 8; ++h)
        af[h] = *(const h8*)(S + (size_t)g * 8192 + (size_t)(h * 64 + lane) * 8);
    __syncthreads();

    const float* Wop = Wo + w * 64 + l15;
    f4 acc[4] = {{0.f,0.f,0.f,0.f},{0.f,0.f,0.f,0.f},
                 {0.f,0.f,0.f,0.f},{0.f,0.f,0.f,0.f}};
    #pragma unroll
    for (int h = 0; h < 8; ++h) {
        h8 bf[4];
        #pragma unroll
        for (int tt = 0; tt < 4; ++tt)
            #pragma unroll
            for (int j = 0; j < 8; ++j)
                bf[tt][j] = (f16)Wop[(size_t)(h * 32 + quad * 8 + j) * DIN + tt * 16];
        #pragma unroll
        for (int tt = 0; tt < 4; ++tt)
            acc[tt] = __builtin_amdgcn_mfma_f32_16x16x32_f16(af[h], bf[tt], acc[tt], 0, 0, 0);
    }
    #pragma unroll
    for (int tt = 0; tt < 4; ++tt) {
        const int c = w * 64 + tt * 16 + l15;
        const float bb = bo[c];
        #pragma unroll
        for (int r = 0; r < 4; ++r)
            outbuf[(size_t)(g * 16 + quad * 4 + r) * DIN + c] = acc[tt][r] + bb;
    }
}

// ===========================================================================
extern "C" void kernel_launch(void* const* d_in, const int* in_sizes, int n_in,
                              void* d_out, int out_size, void* d_ws, size_t ws_size,
                              hipStream_t stream) {
    (void)in_sizes; (void)n_in; (void)out_size;
    const float* Xq = (const float*)d_in[0];
    const float* Xk = (const float*)d_in[1];
    const float* Xv = (const float*)d_in[2];
    const int*  mask = (const int*)d_in[3];
    const float* Wq = (const float*)d_in[4];
    const float* bq = (const float*)d_in[5];
    const float* Wk = (const float*)d_in[6];
    const float* bk = (const float*)d_in[7];
    const float* Wv = (const float*)d_in[8];
    const float* bv = (const float*)d_in[9];
    const float* Wo = (const float*)d_in[10];
    const float* bo = (const float*)d_in[11];
    float* out = (float*)d_out;

    const size_t HB_E = (size_t)Bn * Hn * Ln * DEPTH;     // 1M f16 each
    const size_t need = 3 * HB_E * sizeof(f16);           // 6 MB

    if (ws_size >= need) {
        // Main path: 2 dispatches (ws poison is an unconditional tax).
        f16* Qz = (f16*)d_ws;
        f16* Kz = Qz + HB_E;
        f16* Vz = Kz + HB_E;
        proj_gemm<<<dim3(Bn * Ln / 64, DIN / 64, 3), 256, 0, stream>>>(
            Xq, Xk, Xv, Wq, Wk, Wv, bq, bk, bv, Qz, Kz, Vz);
        flash_out<<<Bn * Ln / 32, 1024, 0, stream>>>(
            Qz, Kz, Vz, mask, Wo, bo, out);
    } else {
        // Proven R4 zero-workspace self-aliasing path.
        f16* S = (f16*)out;
        fb_projKV<<<dim3(16, 4, 2), 256, 0, stream>>>(Xk, Xv, Wk, Wv, bk, bv, S, 0);
        fb_flashQ<<<dim3(8, 32), 512, 0, stream>>>(Xq, Wq, bq, mask, out, 0);
        fb_projKV<<<dim3(16, 4, 2), 256, 0, stream>>>(Xk, Xv, Wk, Wv, bk, bv, S, 1);
        fb_flashQ<<<dim3(8, 32), 512, 0, stream>>>(Xq, Wq, bq, mask, out, 1);
        fb_outproj<<<256, 256, 0, stream>>>(Wo, bo, out);
    }
}

// Round 8
// 125.699 us; speedup vs baseline: 1.0661x; 1.0661x over previous
//
#include <hip/hip_runtime.h>

#define Bn 2
#define Ln 2048
#define DIN 256
#define Hn 8
#define DEPTH 32
#define SCALE 0.17677669529663687f      // 1/sqrt(32)
#define QSCL (0.17677669529663687f * 1.4426950408889634f)  // SCALE*log2(e)
#define NEGC (-4294967296.0f)           // float32(-2^32+1)
#define NG  (Ln / 16)                   // 128 16-row groups per (b,h)
#define WLS 264                         // LDS W^T row stride (f16) [fallback]

typedef _Float16 f16;
typedef _Float16 h8 __attribute__((ext_vector_type(8)));   // K=32 A/B frag
typedef _Float16 h4 __attribute__((ext_vector_type(4)));   // K=16 A/B frag
typedef float f4 __attribute__((ext_vector_type(4)));      // C/D frag

// ===========================================================================
// MAIN PATH (ws >= 8 MB). Budget model (R0-R7): fill ~42us unconditional tax,
// restore/launch train ~50us, kernels ~30us vs ~18us floor.  R7 lesson:
// fusing flash+out halves the grid and quadruples the serial chain -> keep
// the R6 3-launch structure (best measured, 121.2us) and shave the flash
// critical path instead.
//   L1 proj_gemm (768 blk, no-LDS): QKV -> Qz (pre-scaled by SCALE*log2e),
//       Kz, Vz in ws
//   L2 flash_mfma (1024 blk x 512 thr, 8-way split-K, XCD-swizzled): the
//       softmax exp is now a bare v_exp_f32 (exp2f) -- log2e folded into Q.
//   L3 out_gemm (512 blk, no-LDS): out-projection -> out
// Frag-swizzled ws layouts (proven):
//   Qz/Kz chunk per (hb, 16-row group g) = 512 f16: lane(quad*16+l15) holds
//     8 f16 = row (g*16+l15), depth (quad*8..+7).
//   Vz per (hb,g): 2 half-chunks of 256 f16 (d-halves); lane holds 4 f16 =
//     V[key=g*16+quad*4+j][d=dhalf*16+l15].
//   Oz chunk per (row-group gm, h) = 512 f16: lane holds O[row=gm*16+l15]
//     [d=quad*8..+7].
// ===========================================================================

// ---- Kernel 1: QKV projection, no LDS. Wave = 16m x 64n tile. -------------
__global__ __launch_bounds__(256) void proj_gemm(
    const float* __restrict__ Xq, const float* __restrict__ Xk, const float* __restrict__ Xv,
    const float* __restrict__ Wq, const float* __restrict__ Wk, const float* __restrict__ Wv,
    const float* __restrict__ bq, const float* __restrict__ bk, const float* __restrict__ bv,
    f16* __restrict__ Qz, f16* __restrict__ Kz, f16* __restrict__ Vz)
{
    const int p = blockIdx.z;
    const float* X = p == 0 ? Xq : p == 1 ? Xk : Xv;
    const float* W = p == 0 ? Wq : p == 1 ? Wk : Wv;
    const float* bias = p == 0 ? bq : p == 1 ? bk : bv;

    const int t = threadIdx.x, w = t >> 6, lane = t & 63;
    const int l15 = lane & 15, quad = lane >> 4;
    const int n0 = blockIdx.y * 64;
    const int m0 = blockIdx.x * 64 + w * 16;

    const float* A0 = X + (size_t)(m0 + l15) * DIN;
    const float* Wp = W + n0 + l15;          // this lane's n-column base

    f4 acc[4] = {{0.f,0.f,0.f,0.f},{0.f,0.f,0.f,0.f},
                 {0.f,0.f,0.f,0.f},{0.f,0.f,0.f,0.f}};
    #pragma unroll
    for (int kk = 0; kk < 8; ++kk) {
        const int k0 = kk * 32;
        float4 xa = *(const float4*)(A0 + k0 + quad * 8);
        float4 xb = *(const float4*)(A0 + k0 + quad * 8 + 4);
        h8 af = { (f16)xa.x, (f16)xa.y, (f16)xa.z, (f16)xa.w,
                  (f16)xb.x, (f16)xb.y, (f16)xb.z, (f16)xb.w };
        h8 bf[4];
        #pragma unroll
        for (int tt = 0; tt < 4; ++tt)
            #pragma unroll
            for (int j = 0; j < 8; ++j)
                bf[tt][j] = (f16)Wp[(size_t)(k0 + quad * 8 + j) * DIN + tt * 16];
        #pragma unroll
        for (int tt = 0; tt < 4; ++tt)
            acc[tt] = __builtin_amdgcn_mfma_f32_16x16x32_f16(af, bf[tt], acc[tt], 0, 0, 0);
    }
    #pragma unroll
    for (int tt = 0; tt < 4; ++tt) {
        const int c = n0 + tt * 16 + l15;        // 16-tile never straddles a head
        const float bb = bias[c];
        const int h = c >> 5, dd = c & 31;
        #pragma unroll
        for (int r = 0; r < 4; ++r) {
            const int row = m0 + quad * 4 + r;
            const int b = row >> 11, l = row & (Ln - 1);
            const float v = acc[tt][r] + bb;
            const size_t hbg = (size_t)(b * Hn + h) * NG + (l >> 4);
            if (p == 0)        // Q swizzled (K=32 B-frag), pre-scaled w/ log2e
                Qz[(hbg * 64 + (dd >> 3) * 16 + (l & 15)) * 8 + (dd & 7)] =
                    (f16)(v * QSCL);
            else if (p == 1)   // K swizzled (K=32 A-frag chunks)
                Kz[(hbg * 64 + (dd >> 3) * 16 + (l & 15)) * 8 + (dd & 7)] = (f16)v;
            else               // V swizzled (K=16 A-frag chunks, 2 d-halves)
                Vz[((hbg * 2 + (dd >> 4)) * 64 + ((l & 15) >> 2) * 16 + (dd & 15)) * 4
                   + (l & 3)] = (f16)v;
        }
    }
}

// ---- Kernel 2: 8-way split-K MFMA flash, 32 q-rows/block, XCD-swizzled. ---
// 1D grid 1024: swz = (bid&7)*128 + bid>>3 (bijective); hb = swz>>6, qc = swz&63.
// Wave w covers keys [w*256, (w+1)*256) = 16 groups.  Softmax exp = exp2f
// (log2e pre-folded into Qz) -> bare v_exp_f32 on the critical chain.
__global__ __launch_bounds__(512) void flash_mfma(
    const f16* __restrict__ Qz, const f16* __restrict__ Kz,
    const f16* __restrict__ Vz, const int* __restrict__ mask,
    f16* __restrict__ Oz)
{
    __shared__ float Os[8][32][34];    // 34.8 KB, partial O^T [w][d][q]
    __shared__ float lS[8][32];
    const int t = threadIdx.x, w = t >> 6, lane = t & 63;
    const int l15 = lane & 15, quad = lane >> 4;
    const int bid = blockIdx.x;
    const int swz = (bid & 7) * 128 + (bid >> 3);
    const int hb = swz >> 6, qc = swz & 63;        // h=hb&7, b=hb>>3
    const int q0 = qc * 32;
    const int b = hb >> 3, h = hb & 7;
    const f16* Qh = Qz + (size_t)hb * NG * 512;    // 512 f16 per group chunk
    const f16* Kh = Kz + (size_t)hb * NG * 512;
    const f16* Vh = Vz + (size_t)hb * NG * 512;    // 2 half-chunks of 256 f16/group
    const int* mrow = mask + b * Ln;
    const int k_base = w * (Ln / 8);

    h8 qf[2];                                   // coalesced 1024B chunk loads
    #pragma unroll
    for (int qg = 0; qg < 2; ++qg)
        qf[qg] = *(const h8*)(Qh + ((size_t)(qc * 2 + qg) * 64 + lane) * 8);

    f4 o[2][2];                                 // [d-group][q-group]
    #pragma unroll
    for (int i = 0; i < 2; ++i)
        #pragma unroll
        for (int j = 0; j < 2; ++j) o[i][j] = (f4){0.f, 0.f, 0.f, 0.f};
    float l_run[2] = {0.f, 0.f};                // per-lane q = q0 + qg*16 + l15

    for (int kt = 0; kt < Ln / 8 / 64; ++kt) {  // 4 iters x 4 groups
        const int k0 = k_base + kt * 64;
        #pragma unroll
        for (int tt = 0; tt < 4; ++tt) {
            const int g = (k0 >> 4) + tt;
            // coalesced: kf 1024B, va 512B each, mask 64B
            h8 kf = *(const h8*)(Kh + ((size_t)g * 64 + lane) * 8);
            const int4 mk = *(const int4*)(mrow + g * 16 + quad * 4);
            f4 bias4 = { mk.x ? 0.f : NEGC, mk.y ? 0.f : NEGC,
                         mk.z ? 0.f : NEGC, mk.w ? 0.f : NEGC };
            h4 va0 = *(const h4*)(Vh + ((size_t)(g * 2)     * 64 + lane) * 4);
            h4 va1 = *(const h4*)(Vh + ((size_t)(g * 2 + 1) * 64 + lane) * 4);
            f4 s[2];
            #pragma unroll
            for (int qg = 0; qg < 2; ++qg)
                s[qg] = __builtin_amdgcn_mfma_f32_16x16x32_f16(kf, qf[qg], bias4, 0, 0, 0);
            #pragma unroll
            for (int qg = 0; qg < 2; ++qg) {
                h4 pf;
                #pragma unroll
                for (int r = 0; r < 4; ++r) {
                    const float pv = exp2f(s[qg][r]);   // bare v_exp_f32
                    l_run[qg] += pv;
                    pf[r] = (f16)pv;
                }
                o[0][qg] = __builtin_amdgcn_mfma_f32_16x16x16f16(va0, pf, o[0][qg], 0, 0, 0);
                o[1][qg] = __builtin_amdgcn_mfma_f32_16x16x16f16(va1, pf, o[1][qg], 0, 0, 0);
            }
        }
    }
    // ---- wave partials ----
    #pragma unroll
    for (int qg = 0; qg < 2; ++qg) {
        l_run[qg] += __shfl_xor(l_run[qg], 16, 64);
        l_run[qg] += __shfl_xor(l_run[qg], 32, 64);
        if (quad == 0) lS[w][qg * 16 + l15] = l_run[qg];
        #pragma unroll
        for (int dg = 0; dg < 2; ++dg)
            #pragma unroll
            for (int r = 0; r < 4; ++r)
                Os[w][dg * 16 + quad * 4 + r][qg * 16 + l15] = o[dg][qg][r];
    }
    __syncthreads();

    // ---- combine 8 chunks -> Oz chunk (gm = global row>>4, h) ----
    if (t < 128) {
        const int cq = t & 31, dv = t >> 5;      // dv = depth quad 0..3
        float ls = 0.f;
        #pragma unroll
        for (int i = 0; i < 8; ++i) ls += lS[i][cq];
        const float inv = 1.0f / ls;
        h8 pack;
        #pragma unroll
        for (int i = 0; i < 8; ++i) {
            const int dd = dv * 8 + i;
            float ov = 0.f;
            #pragma unroll
            for (int s = 0; s < 8; ++s) ov += Os[s][dd][cq];
            pack[i] = (f16)(ov * inv);
        }
        const int gm = b * NG + ((q0 + cq) >> 4);      // global-row group
        *(h8*)(Oz + (((size_t)gm * 8 + h) * 64 + dv * 16 + (cq & 15)) * 8) = pack;
    }
}

// ---- Kernel 3: out projection, no LDS/barriers. Block = 16 rows x 128 cols.
__global__ __launch_bounds__(256) void out_gemm(
    const f16* __restrict__ Oz, const float* __restrict__ Wo,
    const float* __restrict__ bo, float* __restrict__ out)
{
    const int t = threadIdx.x, w = t >> 6, lane = t & 63;
    const int l15 = lane & 15, quad = lane >> 4;
    const int g = blockIdx.x >> 1, nh = blockIdx.x & 1;   // 16-row group, n-half

    h8 af[8];                                // A-frags: own Oz rows, coalesced
    #pragma unroll
    for (int h = 0; h < 8; ++h)
        af[h] = *(const h8*)(Oz + (((size_t)g * 8 + h) * 64 + lane) * 8);

    const float* Wop = Wo + nh * 128 + w * 32 + l15;   // this wave's 32-col slice
    f4 acc[2] = {{0.f,0.f,0.f,0.f},{0.f,0.f,0.f,0.f}};
    #pragma unroll
    for (int h = 0; h < 8; ++h) {
        h8 bf[2];
        #pragma unroll
        for (int tt = 0; tt < 2; ++tt)
            #pragma unroll
            for (int j = 0; j < 8; ++j)
                bf[tt][j] = (f16)Wop[(size_t)(h * 32 + quad * 8 + j) * DIN + tt * 16];
        #pragma unroll
        for (int tt = 0; tt < 2; ++tt)
            acc[tt] = __builtin_amdgcn_mfma_f32_16x16x32_f16(af[h], bf[tt], acc[tt], 0, 0, 0);
    }
    #pragma unroll
    for (int tt = 0; tt < 2; ++tt) {
        const int c = nh * 128 + w * 32 + tt * 16 + l15;
        const float bb = bo[c];
        #pragma unroll
        for (int r = 0; r < 4; ++r)
            out[(size_t)(g * 16 + quad * 4 + r) * DIN + c] = acc[tt][r] + bb;
    }
}

// ===========================================================================
// FALLBACK (ws < 8 MB): proven R4 zero-workspace self-aliasing 5-launch path.
// (Self-contained numerics: keeps SCALE + __expf.)
// ===========================================================================
__global__ __launch_bounds__(256) void fb_projKV(
    const float* __restrict__ Xk, const float* __restrict__ Xv,
    const float* __restrict__ Wk, const float* __restrict__ Wv,
    const float* __restrict__ bk, const float* __restrict__ bv,
    f16* S, int b)
{
    __shared__ f16 Wl[64 * WLS];
    const int p = blockIdx.z;
    const float* X = (p ? Xv : Xk) + (size_t)b * Ln * DIN;
    const float* W = p ? Wv : Wk;
    const float* bias = p ? bv : bk;

    const int t = threadIdx.x, w = t >> 6, lane = t & 63;
    const int l15 = lane & 15, quad = lane >> 4;
    const int n0 = blockIdx.y * 64;

    {
        const int nl = t & 63, kb = t >> 6;
        for (int kk = 0; kk < 64; ++kk) {
            const int k = kk * 4 + kb;
            Wl[nl * WLS + k] = (f16)W[(size_t)k * DIN + n0 + nl];
        }
    }
    __syncthreads();

    const int m0w = blockIdx.x * 128 + w * 32;
    const float* A0 = X + (size_t)(m0w + l15) * DIN;
    const float* A1 = X + (size_t)(m0w + 16 + l15) * DIN;

    f4 acc[2][4];
    #pragma unroll
    for (int mi = 0; mi < 2; ++mi)
        #pragma unroll
        for (int tt = 0; tt < 4; ++tt) acc[mi][tt] = (f4){0.f, 0.f, 0.f, 0.f};

    for (int k0 = 0; k0 < DIN; k0 += 32) {
        float4 xa0 = *(const float4*)(A0 + k0 + quad * 8);
        float4 xb0 = *(const float4*)(A0 + k0 + quad * 8 + 4);
        float4 xa1 = *(const float4*)(A1 + k0 + quad * 8);
        float4 xb1 = *(const float4*)(A1 + k0 + quad * 8 + 4);
        h8 af0 = { (f16)xa0.x, (f16)xa0.y, (f16)xa0.z, (f16)xa0.w,
                   (f16)xb0.x, (f16)xb0.y, (f16)xb0.z, (f16)xb0.w };
        h8 af1 = { (f16)xa1.x, (f16)xa1.y, (f16)xa1.z, (f16)xa1.w,
                   (f16)xb1.x, (f16)xb1.y, (f16)xb1.z, (f16)xb1.w };
        #pragma unroll
        for (int tt = 0; tt < 4; ++tt) {
            h8 bf = *(const h8*)(Wl + (tt * 16 + l15) * WLS + k0 + quad * 8);
            acc[0][tt] = __builtin_amdgcn_mfma_f32_16x16x32_f16(af0, bf, acc[0][tt], 0, 0, 0);
            acc[1][tt] = __builtin_amdgcn_mfma_f32_16x16x32_f16(af1, bf, acc[1][tt], 0, 0, 0);
        }
    }
    #pragma unroll
    for (int mi = 0; mi < 2; ++mi)
        #pragma unroll
        for (int tt = 0; tt < 4; ++tt) {
            const int c = n0 + tt * 16 + l15;
            const float bb = bias[c];
            const int h = c >> 5, dd = c & 31;
            #pragma unroll
            for (int r = 0; r < 4; ++r) {
                const int l = m0w + mi * 16 + quad * 4 + r;
                const float v = acc[mi][tt][r] + bb;
                const unsigned hg = (unsigned)h * 128 + (l >> 4);
                unsigned j;
                if (!p)
                    j = (hg * 64 + (unsigned)(dd >> 3) * 16 + (l & 15)) * 8 + (dd & 7);
                else
                    j = 524288u + ((hg * 2 + (dd >> 4)) * 64
                        + (unsigned)((l & 15) >> 2) * 16 + (dd & 15)) * 4 + (l & 3);
                S[(((size_t)(j >> 12)) << 13) + 4096u + (j & 4095u)] = (f16)v;
            }
        }
}

__global__ __launch_bounds__(512) void fb_flashQ(
    const float* __restrict__ Xq, const float* __restrict__ Wq,
    const float* __restrict__ bq, const int* __restrict__ mask,
    float* outbuf, int b)
{
    __shared__ union {
        struct { f16 Wlq[32 * WLS]; f16 Qs[2048]; } a;
        struct { float Os[8][32][68]; float lS[8][64]; } c;
    } sm;
    f16* S = (f16*)outbuf;
    const int t = threadIdx.x, w = t >> 6, lane = t & 63;
    const int l15 = lane & 15, quad = lane >> 4;
    const int h = blockIdx.x, q0 = blockIdx.y * 64;

    {
        const int nl = t & 31, kb = t >> 5;
        for (int kk = 0; kk < 16; ++kk) {
            const int k = kk * 16 + kb;
            sm.a.Wlq[nl * WLS + k] = (f16)Wq[(size_t)k * DIN + h * 32 + nl];
        }
    }
    __syncthreads();

    if (w < 4) {
        const float* A0 = Xq + (size_t)(b * Ln + q0 + w * 16 + l15) * DIN;
        f4 a2[2] = { {0.f,0.f,0.f,0.f}, {0.f,0.f,0.f,0.f} };
        #pragma unroll
        for (int kk = 0; kk < 8; ++kk) {
            const int k0 = kk * 32;
            float4 xa = *(const float4*)(A0 + k0 + quad * 8);
            float4 xb = *(const float4*)(A0 + k0 + quad * 8 + 4);
            h8 af = { (f16)xa.x, (f16)xa.y, (f16)xa.z, (f16)xa.w,
                      (f16)xb.x, (f16)xb.y, (f16)xb.z, (f16)xb.w };
            #pragma unroll
            for (int tt = 0; tt < 2; ++tt) {
                h8 bf = *(const h8*)(sm.a.Wlq + (tt * 16 + l15) * WLS + k0 + quad * 8);
                a2[tt] = __builtin_amdgcn_mfma_f32_16x16x32_f16(af, bf, a2[tt], 0, 0, 0);
            }
        }
        #pragma unroll
        for (int tt = 0; tt < 2; ++tt) {
            const int c = tt * 16 + l15;
            const float bb = bq[h * 32 + c];
            #pragma unroll
            for (int r = 0; r < 4; ++r) {
                const int lc = quad * 4 + r;
                sm.a.Qs[((size_t)w * 64 + (c >> 3) * 16 + lc) * 8 + (c & 7)] =
                    (f16)((a2[tt][r] + bb) * SCALE);
            }
        }
    }
    __syncthreads();
    h8 qf[4];
    #pragma unroll
    for (int qg = 0; qg < 4; ++qg)
        qf[qg] = *(const h8*)(sm.a.Qs + ((size_t)qg * 64 + lane) * 8);
    __syncthreads();

    const int* mrow = mask + b * Ln;
    f4 o[2][4];
    #pragma unroll
    for (int i = 0; i < 2; ++i)
        #pragma unroll
        for (int j = 0; j < 4; ++j) o[i][j] = (f4){0.f, 0.f, 0.f, 0.f};
    float l_run[4] = {0.f, 0.f, 0.f, 0.f};
    const int k_base = w * (Ln / 8);

    for (int kt = 0; kt < Ln / 8 / 64; ++kt) {
        const int k0 = k_base + kt * 64;
        #pragma unroll
        for (int tt = 0; tt < 4; ++tt) {
            const int g = (k0 >> 4) + tt;
            const size_t kaddr = ((size_t)(h * 16 + (g >> 3)) << 13) + 4096u
                               + (size_t)((g & 7) * 512 + lane * 8);
            h8 kf = *(const h8*)(S + kaddr);
            const int4 mk = *(const int4*)(mrow + g * 16 + quad * 4);
            f4 bias4 = { mk.x ? 0.f : NEGC, mk.y ? 0.f : NEGC,
                         mk.z ? 0.f : NEGC, mk.w ? 0.f : NEGC };
            const size_t vaddr = ((size_t)(128 + h * 16 + (g >> 3)) << 13) + 4096u
                               + (size_t)((g & 7) * 512 + lane * 4);
            h4 va0 = *(const h4*)(S + vaddr);
            h4 va1 = *(const h4*)(S + vaddr + 256);
            f4 s_[4];
            #pragma unroll
            for (int qg = 0; qg < 4; ++qg)
                s_[qg] = __builtin_amdgcn_mfma_f32_16x16x32_f16(kf, qf[qg], bias4, 0, 0, 0);
            #pragma unroll
            for (int qg = 0; qg < 4; ++qg) {
                h4 pf;
                #pragma unroll
                for (int r = 0; r < 4; ++r) {
                    const float pv = __expf(s_[qg][r]);
                    l_run[qg] += pv;
                    pf[r] = (f16)pv;
                }
                o[0][qg] = __builtin_amdgcn_mfma_f32_16x16x16f16(va0, pf, o[0][qg], 0, 0, 0);
                o[1][qg] = __builtin_amdgcn_mfma_f32_16x16x16f16(va1, pf, o[1][qg], 0, 0, 0);
            }
        }
    }
    #pragma unroll
    for (int qg = 0; qg < 4; ++qg) {
        l_run[qg] += __shfl_xor(l_run[qg], 16, 64);
        l_run[qg] += __shfl_xor(l_run[qg], 32, 64);
        if (quad == 0) sm.c.lS[w][qg * 16 + l15] = l_run[qg];
        #pragma unroll
        for (int dg = 0; dg < 2; ++dg)
            #pragma unroll
            for (int r = 0; r < 4; ++r)
                sm.c.Os[w][dg * 16 + quad * 4 + r][qg * 16 + l15] = o[dg][qg][r];
    }
    __syncthreads();

    if (t < 256) {
        const int cq = t & 63, dv = t >> 6;
        float ls = 0.f;
        #pragma unroll
        for (int i = 0; i < 8; ++i) ls += sm.c.lS[i][cq];
        const float inv = 1.0f / ls;
        h8 pack;
        #pragma unroll
        for (int i = 0; i < 8; ++i) {
            const int dd = dv * 8 + i;
            float ov = 0.f;
            #pragma unroll
            for (int s = 0; s < 8; ++s) ov += sm.c.Os[s][dd][cq];
            pack[i] = (f16)(ov * inv);
        }
        const int gm = b * 128 + ((q0 + cq) >> 4);
        *(h8*)(S + (size_t)gm * 8192
               + (size_t)(h * 64 + dv * 16 + (cq & 15)) * 8) = pack;
    }
}

__global__ __launch_bounds__(256) void fb_outproj(
    const float* __restrict__ Wo, const float* __restrict__ bo, float* outbuf)
{
    f16* S = (f16*)outbuf;
    const int t = threadIdx.x, w = t >> 6, lane = t & 63;
    const int l15 = lane & 15, quad = lane >> 4;
    const int g = blockIdx.x;

    h8 af[8];
    #pragma unroll
    for (int h = 0; h < 8; ++h)
        af[h] = *(const h8*)(S + (size_t)g * 8192 + (size_t)(h * 64 + lane) * 8);
    __syncthreads();

    const float* Wop = Wo + w * 64 + l15;
    f4 acc[4] = {{0.f,0.f,0.f,0.f},{0.f,0.f,0.f,0.f},
                 {0.f,0.f,0.f,0.f},{0.f,0.f,0.f,0.f}};
    #pragma unroll
    for (int h = 0; h < 8; ++h) {
        h8 bf[4];
        #pragma unroll
        for (int tt = 0; tt < 4; ++tt)
            #pragma unroll
            for (int j = 0; j < 8; ++j)
                bf[tt][j] = (f16)Wop[(size_t)(h * 32 + quad * 8 + j) * DIN + tt * 16];
        #pragma unroll
        for (int tt = 0; tt < 4; ++tt)
            acc[tt] = __builtin_amdgcn_mfma_f32_16x16x32_f16(af[h], bf[tt], acc[tt], 0, 0, 0);
    }
    #pragma unroll
    for (int tt = 0; tt < 4; ++tt) {
        const int c = w * 64 + tt * 16 + l15;
        const float bb = bo[c];
        #pragma unroll
        for (int r = 0; r < 4; ++r)
            outbuf[(size_t)(g * 16 + quad * 4 + r) * DIN + c] = acc[tt][r] + bb;
    }
}

// ===========================================================================
extern "C" void kernel_launch(void* const* d_in, const int* in_sizes, int n_in,
                              void* d_out, int out_size, void* d_ws, size_t ws_size,
                              hipStream_t stream) {
    (void)in_sizes; (void)n_in; (void)out_size;
    const float* Xq = (const float*)d_in[0];
    const float* Xk = (const float*)d_in[1];
    const float* Xv = (const float*)d_in[2];
    const int*  mask = (const int*)d_in[3];
    const float* Wq = (const float*)d_in[4];
    const float* bq = (const float*)d_in[5];
    const float* Wk = (const float*)d_in[6];
    const float* bk = (const float*)d_in[7];
    const float* Wv = (const float*)d_in[8];
    const float* bv = (const float*)d_in[9];
    const float* Wo = (const float*)d_in[10];
    const float* bo = (const float*)d_in[11];
    float* out = (float*)d_out;

    const size_t HB_E = (size_t)Bn * Hn * Ln * DEPTH;     // 1M f16 each
    const size_t need = 4 * HB_E * sizeof(f16);           // 8 MB

    if (ws_size >= need) {
        // Main path: ws poison is unconditional -> using ws is free.
        f16* Qz = (f16*)d_ws;
        f16* Kz = Qz + HB_E;
        f16* Vz = Kz + HB_E;
        f16* Oz = Vz + HB_E;
        proj_gemm<<<dim3(Bn * Ln / 64, DIN / 64, 3), 256, 0, stream>>>(
            Xq, Xk, Xv, Wq, Wk, Wv, bq, bk, bv, Qz, Kz, Vz);
        flash_mfma<<<Ln / 32 * Bn * Hn, 512, 0, stream>>>(Qz, Kz, Vz, mask, Oz);
        out_gemm<<<Bn * Ln / 16 * 2, 256, 0, stream>>>(Oz, Wo, bo, out);
    } else {
        // Proven R4 zero-workspace self-aliasing path.
        f16* S = (f16*)out;
        fb_projKV<<<dim3(16, 4, 2), 256, 0, stream>>>(Xk, Xv, Wk, Wv, bk, bv, S, 0);
        fb_flashQ<<<dim3(8, 32), 512, 0, stream>>>(Xq, Wq, bq, mask, out, 0);
        fb_projKV<<<dim3(16, 4, 2), 256, 0, stream>>>(Xk, Xv, Wk, Wv, bk, bv, S, 1);
        fb_flashQ<<<dim3(8, 32), 512, 0, stream>>>(Xq, Wq, bq, mask, out, 1);
        fb_outproj<<<256, 256, 0, stream>>>(Wo, bo, out);
    }
}